// Round 2
// baseline (1073.698 us; speedup 1.0000x reference)
//
#include <hip/hip_runtime.h>
#include <hip/hip_bf16.h>

typedef __bf16 bf16_t;
typedef __bf16 bf16x8 __attribute__((ext_vector_type(8)));
typedef float f32x4 __attribute__((ext_vector_type(4)));

#define B_  4
#define S_  2048
#define H_  16
#define DK_ 128
#define DM_ 2048
#define BS_ (B_ * S_)          // 8192 rows

static __device__ __forceinline__ f32x4 mfma16(bf16x8 a, bf16x8 b, f32x4 c) {
  return __builtin_amdgcn_mfma_f32_16x16x32_bf16(a, b, c, 0, 0, 0);
}

// load 8 consecutive elements as bf16x8, converting fp32 -> bf16 if needed
static __device__ __forceinline__ bf16x8 load8(const bf16_t* p) {
  return *(const bf16x8*)p;
}
static __device__ __forceinline__ bf16x8 load8(const float* p) {
  const float4 f0 = ((const float4*)p)[0];
  const float4 f1 = ((const float4*)p)[1];
  bf16x8 r;
  r[0] = (bf16_t)f0.x; r[1] = (bf16_t)f0.y; r[2] = (bf16_t)f0.z; r[3] = (bf16_t)f0.w;
  r[4] = (bf16_t)f1.x; r[5] = (bf16_t)f1.y; r[6] = (bf16_t)f1.z; r[7] = (bf16_t)f1.w;
  return r;
}

// ---------------------------------------------------------------------------
// C[M,N] = A[M,K] * B[N,K]^T (k-contiguous operands), fp32 accumulate.
// TA/TB in {float, bf16_t} (converted to bf16 at staging), TC = float or bf16.
// VTOUT: write C transposed per-head into Vt layout [(b*16+h)*128+d][s].
// 128x128 tile, 4 waves 2x2, each wave 64x64 via 4x4 of 16x16x32 MFMAs, BK=32.
// ---------------------------------------------------------------------------
template <typename TA, typename TB, typename TC, bool VTOUT>
__global__ __launch_bounds__(256) void gemm_bt(const TA* __restrict__ A,
                                               const TB* __restrict__ B,
                                               TC* __restrict__ C,
                                               int M, int N, int K) {
  __shared__ bf16_t As[128 * 32];
  __shared__ bf16_t Bs[128 * 32];

  const int tid  = threadIdx.x;
  const int wave = tid >> 6;
  const int lane = tid & 63;
  const int quad = lane >> 4;
  const int l16  = lane & 15;
  const int wm   = (wave & 1) * 64;
  const int wn   = (wave >> 1) * 64;
  const int bm   = blockIdx.x * 128;
  const int bn   = blockIdx.y * 128;

  const int ld_row = tid >> 2;        // 0..63 (and +64)
  const int ld_col = (tid & 3) * 8;   // 0,8,16,24

  f32x4 acc[4][4];
#pragma unroll
  for (int i = 0; i < 4; ++i)
#pragma unroll
    for (int j = 0; j < 4; ++j) acc[i][j] = (f32x4){0.f, 0.f, 0.f, 0.f};

  for (int k0 = 0; k0 < K; k0 += 32) {
    const TA* Ap = A + (size_t)(bm + ld_row) * K + k0 + ld_col;
    const TB* Bp = B + (size_t)(bn + ld_row) * K + k0 + ld_col;
    bf16x8 a0 = load8(Ap);
    bf16x8 a1 = load8(Ap + (size_t)64 * K);
    bf16x8 b0 = load8(Bp);
    bf16x8 b1 = load8(Bp + (size_t)64 * K);
    __syncthreads();               // previous iteration's LDS reads done
    *(bf16x8*)(As + ld_row * 32 + ld_col)        = a0;
    *(bf16x8*)(As + (ld_row + 64) * 32 + ld_col) = a1;
    *(bf16x8*)(Bs + ld_row * 32 + ld_col)        = b0;
    *(bf16x8*)(Bs + (ld_row + 64) * 32 + ld_col) = b1;
    __syncthreads();

    bf16x8 af[4], bfr[4];
#pragma unroll
    for (int mt = 0; mt < 4; ++mt)
      af[mt] = *(const bf16x8*)(As + (wm + mt * 16 + l16) * 32 + quad * 8);
#pragma unroll
    for (int nt = 0; nt < 4; ++nt)
      bfr[nt] = *(const bf16x8*)(Bs + (wn + nt * 16 + l16) * 32 + quad * 8);
#pragma unroll
    for (int mt = 0; mt < 4; ++mt)
#pragma unroll
      for (int nt = 0; nt < 4; ++nt)
        acc[mt][nt] = mfma16(af[mt], bfr[nt], acc[mt][nt]);
  }

#pragma unroll
  for (int mt = 0; mt < 4; ++mt)
#pragma unroll
    for (int nt = 0; nt < 4; ++nt)
#pragma unroll
      for (int v = 0; v < 4; ++v) {
        int row = bm + wm + mt * 16 + quad * 4 + v;
        int col = bn + wn + nt * 16 + l16;
        if constexpr (VTOUT) {
          // row = b*S+s, col = h*128+d  ->  Vt[((b*16+h)*128+d)*S + s]
          size_t o = (size_t)(((row >> 11) * 16 + (col >> 7)) * 128 + (col & 127)) * S_ +
                     (row & 2047);
          C[o] = (TC)acc[mt][nt][v];
        } else {
          C[(size_t)row * N + col] = (TC)acc[mt][nt][v];
        }
      }
}

// ---------------------------------------------------------------------------
// Flash attention: one workgroup per (64-query block, b, h). 4 waves, each
// owns 16 query rows. Online softmax. Causal mask optional (device-read).
// Q,K: [b*S+s][h*128+d] bf16.  VT: [(b*16+h)*128+d][s] bf16.  O like Q.
// ---------------------------------------------------------------------------
__global__ __launch_bounds__(256) void attn_kernel(const bf16_t* __restrict__ Q,
                                                   const bf16_t* __restrict__ K,
                                                   const bf16_t* __restrict__ VT,
                                                   bf16_t* __restrict__ O,
                                                   const int* __restrict__ use_mask) {
  __shared__ bf16_t Qs[64 * 136];    // [q][d]
  __shared__ bf16_t Ks[64 * 136];    // [k][d]
  __shared__ bf16_t Vs[128 * 72];    // [d][k]
  __shared__ bf16_t Ps[4 * 16 * 72]; // per-wave [q][k]

  const int tid  = threadIdx.x;
  const int wave = tid >> 6;
  const int lane = tid & 63;
  const int quad = lane >> 4;
  const int l16  = lane & 15;

  const int qb = blockIdx.x;         // 0..31
  const int bh = blockIdx.y;         // 0..63
  const int b = bh >> 4, h = bh & 15;
  const int maskflag = *use_mask;

  const size_t qk_base = ((size_t)b * S_ + (size_t)qb * 64) * DM_ + h * DK_;

  // stage Q tile [64][128]
#pragma unroll
  for (int p = 0; p < 4; ++p) {
    int idx = p * 2048 + tid * 8;
    int r = idx >> 7, c = idx & 127;
    bf16x8 t = *(const bf16x8*)(Q + qk_base + (size_t)r * DM_ + c);
    *(bf16x8*)(Qs + r * 136 + c) = t;
  }

  f32x4 acc[8];
#pragma unroll
  for (int i = 0; i < 8; ++i) acc[i] = (f32x4){0.f, 0.f, 0.f, 0.f};
  float mrow[4], lrow[4];
#pragma unroll
  for (int v = 0; v < 4; ++v) { mrow[v] = -INFINITY; lrow[v] = 0.f; }

  bf16x8 qf[4];
  bool qf_loaded = false;
  bf16_t* Pw = Ps + wave * 16 * 72;

  const int nblocks = maskflag ? (qb + 1) : (S_ / 64);
  const float scale = 0.08838834764831845f;   // 1/sqrt(128)

  for (int j = 0; j < nblocks; ++j) {
    __syncthreads();   // prev iteration's LDS reads complete (also Q stage)

    const size_t k_base = ((size_t)b * S_ + (size_t)j * 64) * DM_ + h * DK_;
#pragma unroll
    for (int p = 0; p < 4; ++p) {
      int idx = p * 2048 + tid * 8;
      int r = idx >> 7, c = idx & 127;
      bf16x8 t = *(const bf16x8*)(K + k_base + (size_t)r * DM_ + c);
      *(bf16x8*)(Ks + r * 136 + c) = t;
    }
    const size_t v_base = ((size_t)bh * DK_) * S_ + (size_t)j * 64;
#pragma unroll
    for (int p = 0; p < 4; ++p) {
      int idx = p * 2048 + tid * 8;
      int dr = idx >> 6, kc = idx & 63;
      bf16x8 t = *(const bf16x8*)(VT + v_base + (size_t)dr * S_ + kc);
      *(bf16x8*)(Vs + dr * 72 + kc) = t;
    }
    __syncthreads();

    if (!qf_loaded) {
#pragma unroll
      for (int kk = 0; kk < 4; ++kk)
        qf[kk] = *(const bf16x8*)(Qs + (wave * 16 + l16) * 136 + kk * 32 + quad * 8);
      qf_loaded = true;
    }

    // S = Q K^T : 16 queries x 64 keys
    f32x4 s[4];
#pragma unroll
    for (int nt = 0; nt < 4; ++nt) s[nt] = (f32x4){0.f, 0.f, 0.f, 0.f};
#pragma unroll
    for (int kk = 0; kk < 4; ++kk) {
#pragma unroll
      for (int nt = 0; nt < 4; ++nt) {
        bf16x8 kf = *(const bf16x8*)(Ks + (nt * 16 + l16) * 136 + kk * 32 + quad * 8);
        s[nt] = mfma16(qf[kk], kf, s[nt]);
      }
    }

    // scale + causal mask.  C/D layout: row(query)=quad*4+v, col(key)=l16.
    float sv[4][4];
#pragma unroll
    for (int nt = 0; nt < 4; ++nt)
#pragma unroll
      for (int v = 0; v < 4; ++v) {
        float x = s[nt][v] * scale;
        if (maskflag && j == qb) {
          int kg = nt * 16 + l16;
          int qg = wave * 16 + quad * 4 + v;
          if (kg > qg) x = -INFINITY;
        }
        sv[nt][v] = x;
      }

    // online softmax per query row (reduce across the quad's 16 lanes)
    float pr[4][4];
#pragma unroll
    for (int v = 0; v < 4; ++v) {
      float r = fmaxf(fmaxf(sv[0][v], sv[1][v]), fmaxf(sv[2][v], sv[3][v]));
      r = fmaxf(r, __shfl_xor(r, 1));
      r = fmaxf(r, __shfl_xor(r, 2));
      r = fmaxf(r, __shfl_xor(r, 4));
      r = fmaxf(r, __shfl_xor(r, 8));
      float mnew  = fmaxf(mrow[v], r);
      float alpha = __expf(mrow[v] - mnew);
      float rs = 0.f;
#pragma unroll
      for (int nt = 0; nt < 4; ++nt) {
        float p = __expf(sv[nt][v] - mnew);
        pr[nt][v] = p;
        rs += p;
      }
      rs += __shfl_xor(rs, 1);
      rs += __shfl_xor(rs, 2);
      rs += __shfl_xor(rs, 4);
      rs += __shfl_xor(rs, 8);
      lrow[v] = lrow[v] * alpha + rs;
      mrow[v] = mnew;
#pragma unroll
      for (int dt = 0; dt < 8; ++dt) acc[dt][v] *= alpha;
    }

    // P: C/D layout -> A-operand layout via LDS round trip
#pragma unroll
    for (int nt = 0; nt < 4; ++nt)
#pragma unroll
      for (int v = 0; v < 4; ++v)
        Pw[(quad * 4 + v) * 72 + nt * 16 + l16] = (bf16_t)pr[nt][v];

    __syncthreads();   // uniform control flow; orders P write before read

    // O += P V : 8 d-tiles, 64 keys (2 k-steps)
#pragma unroll
    for (int kk = 0; kk < 2; ++kk) {
      bf16x8 pf = *(const bf16x8*)(Pw + l16 * 72 + kk * 32 + quad * 8);
#pragma unroll
      for (int dt = 0; dt < 8; ++dt) {
        bf16x8 vf = *(const bf16x8*)(Vs + (dt * 16 + l16) * 72 + kk * 32 + quad * 8);
        acc[dt] = mfma16(pf, vf, acc[dt]);
      }
    }
  }

  // epilogue: O[q][d] = acc / l
#pragma unroll
  for (int dt = 0; dt < 8; ++dt)
#pragma unroll
    for (int v = 0; v < 4; ++v) {
      int qr = wave * 16 + quad * 4 + v;
      float o = acc[dt][v] / lrow[v];
      O[qk_base + (size_t)qr * DM_ + dt * 16 + l16] = (bf16_t)o;
    }
}

// ---------------------------------------------------------------------------
extern "C" void kernel_launch(void* const* d_in, const int* in_sizes, int n_in,
                              void* d_out, int out_size, void* d_ws, size_t ws_size,
                              hipStream_t stream) {
  const float* x  = (const float*)d_in[0];
  const float* Wq = (const float*)d_in[1];
  const float* Wk = (const float*)d_in[2];
  const float* Wv = (const float*)d_in[3];
  const float* Wo = (const float*)d_in[4];
  const int* use_mask = (const int*)d_in[5];
  float* out = (float*)d_out;

  const size_t TSZ = (size_t)BS_ * DM_;   // 16,777,216 elements
  bf16_t* Qb = (bf16_t*)d_ws;             // 32 MiB
  bf16_t* Kb = Qb + TSZ;                  // 32 MiB
  bf16_t* Vt = Kb + TSZ;                  // 32 MiB, [b,h,d,s]
  bf16_t* Ob = Vt + TSZ;                  // 32 MiB

  dim3 gGemm(BS_ / 128, DM_ / 128);  // (64, 16)
  gemm_bt<float, float, bf16_t, false><<<gGemm, 256, 0, stream>>>(x, Wq, Qb, BS_, DM_, DM_);
  gemm_bt<float, float, bf16_t, false><<<gGemm, 256, 0, stream>>>(x, Wk, Kb, BS_, DM_, DM_);
  gemm_bt<float, float, bf16_t, true ><<<gGemm, 256, 0, stream>>>(x, Wv, Vt, BS_, DM_, DM_);

  dim3 gA(S_ / 64, B_ * H_);         // (32, 64)
  attn_kernel<<<gA, 256, 0, stream>>>(Qb, Kb, Vt, Ob, use_mask);

  gemm_bt<bf16_t, float, float, false><<<gGemm, 256, 0, stream>>>(Ob, Wo, out, BS_, DM_, DM_);
}

// Round 3
// 911.536 us; speedup vs baseline: 1.1779x; 1.1779x over previous
//
#include <hip/hip_runtime.h>
#include <hip/hip_bf16.h>

typedef __bf16 bf16_t;
typedef __bf16 bf16x8 __attribute__((ext_vector_type(8)));
typedef float f32x4 __attribute__((ext_vector_type(4)));

#define B_  4
#define S_  2048
#define H_  16
#define DK_ 128
#define DM_ 2048
#define BS_ (B_ * S_)          // 8192 rows

static __device__ __forceinline__ f32x4 mfma16(bf16x8 a, bf16x8 b, f32x4 c) {
  return __builtin_amdgcn_mfma_f32_16x16x32_bf16(a, b, c, 0, 0, 0);
}

// async global->LDS 16B copy. lds base must be wave-uniform; HW scatters lane*16.
static __device__ __forceinline__ void async_copy16(const bf16_t* g, bf16_t* l) {
  __builtin_amdgcn_global_load_lds(
      (const __attribute__((address_space(1))) void*)g,
      (__attribute__((address_space(3))) void*)l, 16, 0, 0);
}

// ---------------------------------------------------------------------------
// fp32 -> bf16 elementwise convert (8 elems/thread)
// ---------------------------------------------------------------------------
__global__ __launch_bounds__(256) void cvt_bf16(const float* __restrict__ in,
                                                bf16_t* __restrict__ out, int n8) {
  int i = blockIdx.x * 256 + threadIdx.x;
  if (i < n8) {
    const float4* p = (const float4*)in + (size_t)i * 2;
    float4 f0 = p[0], f1 = p[1];
    bf16x8 r;
    r[0] = (bf16_t)f0.x; r[1] = (bf16_t)f0.y; r[2] = (bf16_t)f0.z; r[3] = (bf16_t)f0.w;
    r[4] = (bf16_t)f1.x; r[5] = (bf16_t)f1.y; r[6] = (bf16_t)f1.z; r[7] = (bf16_t)f1.w;
    ((bf16x8*)out)[i] = r;
  }
}

// ---------------------------------------------------------------------------
// C[M,N] = A[M,K] * B[N,K]^T, bf16 in, fp32 acc, TC out. m97-style staging:
// global_load_lds dwordx4 into unpadded 128x32 LDS tiles. 128x128 block tile,
// 4 waves 2x2, each wave 64x64 via 4x4 of 16x16x32 MFMAs. BK=32.
// VTOUT: write C per-head-transposed into Vt layout [(b*16+h)*128+d][s].
// ---------------------------------------------------------------------------
template <typename TC, bool VTOUT>
__global__ __launch_bounds__(256) void gemm_bt(const bf16_t* __restrict__ A,
                                               const bf16_t* __restrict__ B,
                                               TC* __restrict__ C,
                                               int M, int N, int K) {
  __shared__ bf16_t As[128 * 32];
  __shared__ bf16_t Bs[128 * 32];

  const int tid  = threadIdx.x;
  const int wave = tid >> 6;
  const int lane = tid & 63;
  const int quad = lane >> 4;
  const int l16  = lane & 15;
  const int wm   = (wave & 1) * 64;
  const int wn   = (wave >> 1) * 64;
  const int bm   = blockIdx.x * 128;
  const int bn   = blockIdx.y * 128;

  // chunk c covers LDS elems [c*8, c*8+8): row=c>>2, col=(c&3)*8 (stride 32).
  const int c0 = wave * 128 + lane;
  const int c1 = wave * 128 + 64 + lane;
  const int r0 = c0 >> 2, o0 = (c0 & 3) * 8;
  const int r1 = c1 >> 2, o1 = (c1 & 3) * 8;

  const bf16_t* Ar0 = A + (size_t)(bm + r0) * K + o0;
  const bf16_t* Ar1 = A + (size_t)(bm + r1) * K + o1;
  const bf16_t* Br0 = B + (size_t)(bn + r0) * K + o0;
  const bf16_t* Br1 = B + (size_t)(bn + r1) * K + o1;
  bf16_t* as0 = As + wave * 1024;      // wave-uniform LDS bases
  bf16_t* as1 = As + wave * 1024 + 512;
  bf16_t* bs0 = Bs + wave * 1024;
  bf16_t* bs1 = Bs + wave * 1024 + 512;

  f32x4 acc[4][4];
#pragma unroll
  for (int i = 0; i < 4; ++i)
#pragma unroll
    for (int j = 0; j < 4; ++j) acc[i][j] = (f32x4){0.f, 0.f, 0.f, 0.f};

  for (int k0 = 0; k0 < K; k0 += 32) {
    __syncthreads();                 // prior iteration's LDS reads done
    async_copy16(Ar0 + k0, as0);
    async_copy16(Ar1 + k0, as1);
    async_copy16(Br0 + k0, bs0);
    async_copy16(Br1 + k0, bs1);
    __syncthreads();                 // drains vmcnt -> staged data visible

    bf16x8 af[4], bfr[4];
#pragma unroll
    for (int mt = 0; mt < 4; ++mt)
      af[mt] = *(const bf16x8*)(As + (wm + mt * 16 + l16) * 32 + quad * 8);
#pragma unroll
    for (int nt = 0; nt < 4; ++nt)
      bfr[nt] = *(const bf16x8*)(Bs + (wn + nt * 16 + l16) * 32 + quad * 8);
#pragma unroll
    for (int mt = 0; mt < 4; ++mt)
#pragma unroll
      for (int nt = 0; nt < 4; ++nt)
        acc[mt][nt] = mfma16(af[mt], bfr[nt], acc[mt][nt]);
  }

#pragma unroll
  for (int mt = 0; mt < 4; ++mt)
#pragma unroll
    for (int nt = 0; nt < 4; ++nt)
#pragma unroll
      for (int v = 0; v < 4; ++v) {
        int row = bm + wm + mt * 16 + quad * 4 + v;
        int col = bn + wn + nt * 16 + l16;
        if constexpr (VTOUT) {
          // row = b*S+s, col = h*128+d -> Vt[((b*16+h)*128+d)*S + s]
          size_t o = (size_t)(((row >> 11) * 16 + (col >> 7)) * 128 + (col & 127)) * S_ +
                     (row & 2047);
          C[o] = (TC)acc[mt][nt][v];
        } else {
          C[(size_t)row * N + col] = (TC)acc[mt][nt][v];
        }
      }
}

// ---------------------------------------------------------------------------
// Flash attention: one workgroup per (64-query block, b, h), 4 waves x 16
// query rows, online softmax (exp2 domain). P-scratch aliases the Q stage
// buffer (Q fragments register-resident; P is wave-private). 2 barriers/iter.
// Q,K: [b*S+s][h*128+d] bf16.  VT: [(b*16+h)*128+d][s] bf16.  O like Q.
// ---------------------------------------------------------------------------
__global__ __launch_bounds__(256) void attn_kernel(const bf16_t* __restrict__ Q,
                                                   const bf16_t* __restrict__ K,
                                                   const bf16_t* __restrict__ VT,
                                                   bf16_t* __restrict__ O,
                                                   const int* __restrict__ use_mask) {
  __shared__ bf16_t Ks[64 * 136];    // [k][d]
  __shared__ bf16_t Vs[128 * 72];    // [d][k]
  __shared__ bf16_t QPs[64 * 136];   // Q stage, then per-wave P [16][72]

  const int tid  = threadIdx.x;
  const int wave = tid >> 6;
  const int lane = tid & 63;
  const int quad = lane >> 4;
  const int l16  = lane & 15;

  const int qb = (int)gridDim.x - 1 - (int)blockIdx.x;  // heavy blocks first
  const int bh = blockIdx.y;
  const int b = bh >> 4, h = bh & 15;
  const int maskflag = *use_mask;

  const size_t qk_base = ((size_t)b * S_ + (size_t)qb * 64) * DM_ + h * DK_;

  // stage Q tile [64][128] then preload fragments to registers
#pragma unroll
  for (int p = 0; p < 4; ++p) {
    int idx = p * 2048 + tid * 8;
    int r = idx >> 7, c = idx & 127;
    *(bf16x8*)(QPs + r * 136 + c) = *(const bf16x8*)(Q + qk_base + (size_t)r * DM_ + c);
  }
  __syncthreads();
  bf16x8 qf[4];
#pragma unroll
  for (int kk = 0; kk < 4; ++kk)
    qf[kk] = *(const bf16x8*)(QPs + (wave * 16 + l16) * 136 + kk * 32 + quad * 8);

  f32x4 acc[8];
#pragma unroll
  for (int i = 0; i < 8; ++i) acc[i] = (f32x4){0.f, 0.f, 0.f, 0.f};
  float mrow[4], lrow[4];
#pragma unroll
  for (int v = 0; v < 4; ++v) { mrow[v] = -INFINITY; lrow[v] = 0.f; }

  bf16_t* Pw = QPs + wave * 1152;    // wave-private 16x72

  // softmax in exp2 domain: p = 2^(s*scale*log2e - m)
  const float c1 = 0.08838834764831845f * 1.4426950408889634f;

  auto tile = [&](int j, bool masked) __attribute__((always_inline)) {
    __syncthreads();   // prev iteration's Ks/Vs reads complete (and Q preload)

    const size_t k_base = ((size_t)b * S_ + (size_t)j * 64) * DM_ + h * DK_;
#pragma unroll
    for (int p = 0; p < 4; ++p) {
      int idx = p * 2048 + tid * 8;
      int r = idx >> 7, c = idx & 127;
      *(bf16x8*)(Ks + r * 136 + c) = *(const bf16x8*)(K + k_base + (size_t)r * DM_ + c);
    }
    const size_t v_base = ((size_t)bh * DK_) * S_ + (size_t)j * 64;
#pragma unroll
    for (int p = 0; p < 4; ++p) {
      int idx = p * 2048 + tid * 8;
      int dr = idx >> 6, kc = idx & 63;
      *(bf16x8*)(Vs + dr * 72 + kc) = *(const bf16x8*)(VT + v_base + (size_t)dr * S_ + kc);
    }
    __syncthreads();

    // S = Q K^T : 16 queries x 64 keys
    f32x4 s[4];
#pragma unroll
    for (int nt = 0; nt < 4; ++nt) s[nt] = (f32x4){0.f, 0.f, 0.f, 0.f};
#pragma unroll
    for (int kk = 0; kk < 4; ++kk) {
#pragma unroll
      for (int nt = 0; nt < 4; ++nt) {
        bf16x8 kf = *(const bf16x8*)(Ks + (nt * 16 + l16) * 136 + kk * 32 + quad * 8);
        s[nt] = mfma16(qf[kk], kf, s[nt]);
      }
    }

    // scale (+mask). C/D layout: row(query)=quad*4+v, col(key)=l16.
    float sv[4][4];
#pragma unroll
    for (int nt = 0; nt < 4; ++nt)
#pragma unroll
      for (int v = 0; v < 4; ++v) {
        float x = s[nt][v] * c1;
        if (masked) {
          int kg = nt * 16 + l16;
          int qg = wave * 16 + quad * 4 + v;
          if (kg > qg) x = -INFINITY;
        }
        sv[nt][v] = x;
      }

    // online softmax per query row (reduce across the quad's 16 lanes)
    float pr[4][4];
#pragma unroll
    for (int v = 0; v < 4; ++v) {
      float r = fmaxf(fmaxf(sv[0][v], sv[1][v]), fmaxf(sv[2][v], sv[3][v]));
      r = fmaxf(r, __shfl_xor(r, 1));
      r = fmaxf(r, __shfl_xor(r, 2));
      r = fmaxf(r, __shfl_xor(r, 4));
      r = fmaxf(r, __shfl_xor(r, 8));
      float mnew  = fmaxf(mrow[v], r);
      float alpha = __builtin_amdgcn_exp2f(mrow[v] - mnew);
      float rs = 0.f;
#pragma unroll
      for (int nt = 0; nt < 4; ++nt) {
        float p = __builtin_amdgcn_exp2f(sv[nt][v] - mnew);
        pr[nt][v] = p;
        rs += p;
      }
      rs += __shfl_xor(rs, 1);
      rs += __shfl_xor(rs, 2);
      rs += __shfl_xor(rs, 4);
      rs += __shfl_xor(rs, 8);
      lrow[v] = lrow[v] * alpha + rs;
      mrow[v] = mnew;
#pragma unroll
      for (int dt = 0; dt < 8; ++dt) acc[dt][v] *= alpha;
    }

    // P: C/D layout -> A-operand layout (wave-private LDS; lgkmcnt orders it)
#pragma unroll
    for (int nt = 0; nt < 4; ++nt)
#pragma unroll
      for (int v = 0; v < 4; ++v)
        Pw[(quad * 4 + v) * 72 + nt * 16 + l16] = (bf16_t)pr[nt][v];

    // O += P V : 8 d-tiles, 64 keys (2 k-steps)
#pragma unroll
    for (int kk = 0; kk < 2; ++kk) {
      bf16x8 pf = *(const bf16x8*)(Pw + l16 * 72 + kk * 32 + quad * 8);
#pragma unroll
      for (int dt = 0; dt < 8; ++dt) {
        bf16x8 vf = *(const bf16x8*)(Vs + (dt * 16 + l16) * 72 + kk * 32 + quad * 8);
        acc[dt] = mfma16(pf, vf, acc[dt]);
      }
    }
  };

  const int nfull = maskflag ? qb : (S_ / 64);
  for (int j = 0; j < nfull; ++j) tile(j, false);
  if (maskflag) tile(qb, true);

  // epilogue: O[q][d] = acc / l
#pragma unroll
  for (int dt = 0; dt < 8; ++dt)
#pragma unroll
    for (int v = 0; v < 4; ++v) {
      int qr = wave * 16 + quad * 4 + v;
      float o = acc[dt][v] / lrow[v];
      O[qk_base + (size_t)qr * DM_ + dt * 16 + l16] = (bf16_t)o;
    }
}

// ---------------------------------------------------------------------------
extern "C" void kernel_launch(void* const* d_in, const int* in_sizes, int n_in,
                              void* d_out, int out_size, void* d_ws, size_t ws_size,
                              hipStream_t stream) {
  const float* x  = (const float*)d_in[0];
  const float* Wq = (const float*)d_in[1];
  const float* Wk = (const float*)d_in[2];
  const float* Wv = (const float*)d_in[3];
  const float* Wo = (const float*)d_in[4];
  const int* use_mask = (const int*)d_in[5];
  float* out = (float*)d_out;

  const size_t TSZ = (size_t)BS_ * DM_;   // 16,777,216 elems (32 MiB bf16)
  const size_t WSZ = (size_t)DM_ * DM_;   //  4,194,304 elems ( 8 MiB bf16)
  bf16_t* Qb  = (bf16_t*)d_ws;            // R0
  bf16_t* Kb  = Qb + TSZ;                 // R1
  bf16_t* Vt  = Kb + TSZ;                 // R2: Vt, then Wo_bf16 after attention
  bf16_t* xb  = Vt + TSZ;                 // R3: x_bf16, then Ob after projections
  bf16_t* Ob  = xb;
  bf16_t* Wob = Vt;
  // weight bf16 staging inside d_out (64 MiB fp32; fully overwritten at the end)
  bf16_t* wq = (bf16_t*)d_out;
  bf16_t* wk = wq + WSZ;
  bf16_t* wv = wk + WSZ;

  cvt_bf16<<<(int)(TSZ / 8 / 256), 256, 0, stream>>>(x,  xb, (int)(TSZ / 8));
  cvt_bf16<<<(int)(WSZ / 8 / 256), 256, 0, stream>>>(Wq, wq, (int)(WSZ / 8));
  cvt_bf16<<<(int)(WSZ / 8 / 256), 256, 0, stream>>>(Wk, wk, (int)(WSZ / 8));
  cvt_bf16<<<(int)(WSZ / 8 / 256), 256, 0, stream>>>(Wv, wv, (int)(WSZ / 8));

  dim3 gGemm(BS_ / 128, DM_ / 128);  // (64, 16)
  gemm_bt<bf16_t, false><<<gGemm, 256, 0, stream>>>(xb, wq, Qb, BS_, DM_, DM_);
  gemm_bt<bf16_t, false><<<gGemm, 256, 0, stream>>>(xb, wk, Kb, BS_, DM_, DM_);
  gemm_bt<bf16_t, true ><<<gGemm, 256, 0, stream>>>(xb, wv, Vt, BS_, DM_, DM_);

  dim3 gA(S_ / 64, B_ * H_);         // (32, 64)
  attn_kernel<<<gA, 256, 0, stream>>>(Qb, Kb, Vt, Ob, use_mask);

  cvt_bf16<<<(int)(WSZ / 8 / 256), 256, 0, stream>>>(Wo, Wob, (int)(WSZ / 8));
  gemm_bt<float, false><<<gGemm, 256, 0, stream>>>(Ob, Wob, out, BS_, DM_, DM_);
}